// Round 1
// baseline (1134.795 us; speedup 1.0000x reference)
//
#include <hip/hip_runtime.h>

#define THREADS 256
#define ROWS1   4      // B-rows per pass-1 block
#define VCHUNKS 8      // V split per pass-1 b-tile
#define CFIX    1024   // n_clusters (fixed by setup_inputs; device scalar can't size LDS)

__device__ __forceinline__ float logsigf(float x) {
    // stable log_sigmoid: min(x,0) - log1p(exp(-|x|))
    float ax = fabsf(x);
    float t  = __logf(1.0f + __expf(-ax));
    return fminf(x, 0.0f) - t;
}

__global__ __launch_bounds__(THREADS)
void cls_pass1(const float* __restrict__ logits,
               const int*   __restrict__ cluster,
               float*       __restrict__ sums,   // [B, CFIX], pre-zeroed
               int B, int V) {
    __shared__ float lsum[ROWS1 * CFIX];   // 16 KB
    const int b0 = blockIdx.x * ROWS1;
    for (int i = threadIdx.x; i < ROWS1 * CFIX; i += THREADS) lsum[i] = 0.0f;
    __syncthreads();

    const int chunk   = (V + VCHUNKS - 1) / VCHUNKS;
    const int v_begin = blockIdx.y * chunk;
    const int v_end   = min(V, v_begin + chunk);
    if (v_begin >= v_end) return;
    const int nrows   = min(ROWS1, B - b0);
    const int vlen    = v_end - v_begin;
    // vector path only when the chunk start is 16B-aligned
    const int n4 = ((v_begin & 3) == 0) ? (vlen >> 2) : 0;

    const int4* cl4 = (const int4*)(cluster + v_begin);
    for (int i = threadIdx.x; i < n4; i += THREADS) {
        const int4 c4 = cl4[i];
        const int  v  = v_begin + (i << 2);
        for (int r = 0; r < nrows; ++r) {
            const float4 x = *(const float4*)(logits + (size_t)(b0 + r) * V + v);
            float* ls = lsum + r * CFIX;
            atomicAdd(ls + c4.x, __expf(x.x));
            atomicAdd(ls + c4.y, __expf(x.y));
            atomicAdd(ls + c4.z, __expf(x.z));
            atomicAdd(ls + c4.w, __expf(x.w));
        }
    }
    // scalar tail
    for (int v = v_begin + n4 * 4 + threadIdx.x; v < v_end; v += THREADS) {
        const int c = cluster[v];
        for (int r = 0; r < nrows; ++r)
            atomicAdd(&lsum[r * CFIX + c], __expf(logits[(size_t)(b0 + r) * V + v]));
    }
    __syncthreads();

    // coalesced flush: one global atomic per (row, cluster)
    for (int i = threadIdx.x; i < nrows * CFIX; i += THREADS) {
        const int r = i >> 10;           // i / CFIX
        const int c = i & (CFIX - 1);    // i % CFIX
        atomicAdd(&sums[(size_t)(b0 + r) * CFIX + c], lsum[i]);
    }
}

__global__ __launch_bounds__(THREADS)
void cls_pass2(const float* __restrict__ logits,
               const int*   __restrict__ cluster,
               const float* __restrict__ sums,   // [B, CFIX]
               float*       __restrict__ out,
               int B, int V) {
    __shared__ float ldenom[CFIX];   // 4 KB: log-denominators for this row
    const int b = blockIdx.x;
    const float* srow = sums + (size_t)b * CFIX;
    for (int c = threadIdx.x; c < CFIX; c += THREADS)
        ldenom[c] = __logf(fmaxf(srow[c], 1e-20f));
    __syncthreads();

    const size_t base = (size_t)b * V;
    const int n4 = ((V & 3) == 0) ? (V >> 2) : 0;
    const int4*   cp = (const int4*)cluster;
    const float4* xp = (const float4*)(logits + base);
    float4*       op = (float4*)(out + base);

    for (int i = threadIdx.x; i < n4; i += THREADS) {
        const int4   c = cp[i];
        const float4 x = xp[i];
        float4 o;
        o.x = (c.x == 0) ? logsigf(x.x) : (x.x - ldenom[c.x]);
        o.y = (c.y == 0) ? logsigf(x.y) : (x.y - ldenom[c.y]);
        o.z = (c.z == 0) ? logsigf(x.z) : (x.z - ldenom[c.z]);
        o.w = (c.w == 0) ? logsigf(x.w) : (x.w - ldenom[c.w]);
        op[i] = o;
    }
    for (int v = n4 * 4 + threadIdx.x; v < V; v += THREADS) {
        const int   c = cluster[v];
        const float x = logits[base + v];
        out[base + v] = (c == 0) ? logsigf(x) : (x - ldenom[c]);
    }
}

extern "C" void kernel_launch(void* const* d_in, const int* in_sizes, int n_in,
                              void* d_out, int out_size, void* d_ws, size_t ws_size,
                              hipStream_t stream) {
    const float* logits  = (const float*)d_in[0];
    const int*   cluster = (const int*)d_in[1];
    const int V = in_sizes[1];
    const int B = in_sizes[0] / V;

    float* sums = (float*)d_ws;                       // B*CFIX floats = 4 MB
    hipMemsetAsync(sums, 0, (size_t)B * CFIX * sizeof(float), stream);

    dim3 g1((B + ROWS1 - 1) / ROWS1, VCHUNKS);
    cls_pass1<<<g1, THREADS, 0, stream>>>(logits, cluster, sums, B, V);
    cls_pass2<<<B, THREADS, 0, stream>>>(logits, cluster, sums, (float*)d_out, B, V);
}